// Round 8
// baseline (8522.495 us; speedup 1.0000x reference)
//
#include <hip/hip_runtime.h>

// Problem dims: x[B,T,I], W[H,I], b[H];  B=32, T=2048, I=512, H=1024.
// out = spikes[B,T,H] fp32, then v_f[B,H], then i_f[B,H].
//
// NUMERICS CONTRACT: current[m,n] accumulated as an fp32 fmaf chain over k
// ascending -> bit-identical to reference (absmax 0.0 across R3/R4/R6).
// Spikes are a hard threshold; do NOT reassociate (no split-K, no MFMA).
//
// R7: A (X) in LDS [k][m] (R3-proven, conflict-free); B (W) fragments loaded
// straight from global (L2-resident) with MANUAL one-group-ahead register
// double-buffer (bqX/bqY). R6 failed because in-loop B loads were consumed
// immediately (latency-exposed, VALUBusy 25%); here every load has ~512cy of
// independent FMA cover. LDS demand/kk/CU ~24W cyc < 32W cyc FMA -> compute-
// bound. Regs ~160-190; NO __launch_bounds__ (R4: forcing 2 waves/EU spilled).

static constexpr int BM = 128, BN = 128, BK = 16;

__device__ __forceinline__ void load_b(
    float4 (&dst)[8], const float* wp0, const float* wp1, int K, int koff)
{
#pragma unroll
    for (int r = 0; r < 4; ++r) {
        dst[r]     = *(const float4*)(wp0 + (size_t)r * K + koff);
        dst[r + 4] = *(const float4*)(wp1 + (size_t)r * K + koff);
    }
}

__device__ __forceinline__ void fma_group(
    const float4 (&src)[8],
    const float (*as)[BM + 4],   // pre-offset to this group's first k-row
    int ty,
    float (&acc)[8][8])
{
#pragma unroll
    for (int kk = 0; kk < 4; ++kk) {
        float a[8];
        *(float4*)&a[0] = *(const float4*)&as[kk][ty * 4];
        *(float4*)&a[4] = *(const float4*)&as[kk][ty * 4 + 64];
        float bv[8];
#pragma unroll
        for (int j = 0; j < 8; ++j)
            bv[j] = (kk == 0) ? src[j].x : (kk == 1) ? src[j].y
                  : (kk == 2) ? src[j].z : src[j].w;
#pragma unroll
        for (int i = 0; i < 8; ++i)
#pragma unroll
            for (int j = 0; j < 8; ++j)
                acc[i][j] = fmaf(a[i], bv[j], acc[i][j]);
    }
}

__global__ void snn_gemm_f32(
    const float* __restrict__ X,    // [M,K]
    const float* __restrict__ Wt,   // [N,K]
    const float* __restrict__ bias, // [N]
    float* __restrict__ C,          // [M,N]
    int M, int N, int K)
{
    __shared__ float As[2][BK][BM + 4]; // [k][m], stride 132 floats

    const int tid   = threadIdx.x;
    const int mBase = blockIdx.y * BM;
    const int nBase = blockIdx.x * BN;

    // A loader: each thread brings 2 float4 (rows lrow, lrow+64; k-quad lkq)
    const int lrow = tid >> 2;        // 0..63
    const int lkq  = (tid & 3) << 2;  // 0,4,8,12

    // compute mapping: 16x16 threads, 8x8 micro-tile (split 4+4 at +64)
    const int tx = tid & 15;
    const int ty = tid >> 4;

    const float* Xp = X + (size_t)(mBase + lrow) * K + lkq;
    const size_t Xrow64 = (size_t)64 * K;

    // B row pointers: rows nBase+tx*4+{0..3} and +64 (k-contiguous in W)
    const float* wp0 = Wt + (size_t)(nBase + tx * 4) * K;
    const float* wp1 = wp0 + (size_t)64 * K;

    float acc[8][8];
#pragma unroll
    for (int i = 0; i < 8; ++i)
#pragma unroll
        for (int j = 0; j < 8; ++j) acc[i][j] = 0.f;

    float4 ra0, ra1;
    float4 bqX[8], bqY[8];

    // prologue: stage A k-tile 0 into buffer 0; load B group 0 into bqX
    ra0 = *(const float4*)(Xp);
    ra1 = *(const float4*)(Xp + Xrow64);
    As[0][lkq + 0][lrow] = ra0.x; As[0][lkq + 1][lrow] = ra0.y;
    As[0][lkq + 2][lrow] = ra0.z; As[0][lkq + 3][lrow] = ra0.w;
    As[0][lkq + 0][lrow + 64] = ra1.x; As[0][lkq + 1][lrow + 64] = ra1.y;
    As[0][lkq + 2][lrow + 64] = ra1.z; As[0][lkq + 3][lrow + 64] = ra1.w;
    load_b(bqX, wp0, wp1, K, 0);
    __syncthreads();

    const int nk = K / BK; // 32
#pragma unroll 1
    for (int kt = 0; kt < nk; ++kt) {
        const int cur  = kt & 1;
        const bool more = (kt + 1) < nk;
        const int kb   = kt * BK;
        const int kbn  = more ? (kt + 1) * BK : 0;

        // prefetch next A k-tile into registers (covered by 4 FMA groups)
        if (more) {
            ra0 = *(const float4*)(Xp + kbn);
            ra1 = *(const float4*)(Xp + kbn + Xrow64);
        }

        const float (*as)[BM + 4] = As[cur];

        // phase g0: issue loads for g1 into bqY, compute g0 from bqX
        load_b(bqY, wp0, wp1, K, kb + 4);
        fma_group(bqX, as + 0, ty, acc);
        // phase g1: issue loads for g2 into bqX, compute g1 from bqY
        load_b(bqX, wp0, wp1, K, kb + 8);
        fma_group(bqY, as + 4, ty, acc);
        // phase g2
        load_b(bqY, wp0, wp1, K, kb + 12);
        fma_group(bqX, as + 8, ty, acc);
        // phase g3: issue loads for NEXT kt's g0 into bqX
        load_b(bqX, wp0, wp1, K, kbn);
        fma_group(bqY, as + 12, ty, acc);

        if (more) {
            const int nxt = cur ^ 1;
            As[nxt][lkq + 0][lrow] = ra0.x; As[nxt][lkq + 1][lrow] = ra0.y;
            As[nxt][lkq + 2][lrow] = ra0.z; As[nxt][lkq + 3][lrow] = ra0.w;
            As[nxt][lkq + 0][lrow + 64] = ra1.x; As[nxt][lkq + 1][lrow + 64] = ra1.y;
            As[nxt][lkq + 2][lrow + 64] = ra1.z; As[nxt][lkq + 3][lrow + 64] = ra1.w;
        }
        __syncthreads();
    }

    // epilogue: bias + coalesced float4 stores
    const float4 bb0 = *(const float4*)(bias + nBase + tx * 4);
    const float4 bb1 = *(const float4*)(bias + nBase + tx * 4 + 64);
#pragma unroll
    for (int i = 0; i < 8; ++i) {
        const int m = mBase + ty * 4 + (i & 3) + ((i >> 2) << 6);
        float4 o0, o1;
        o0.x = acc[i][0] + bb0.x; o0.y = acc[i][1] + bb0.y;
        o0.z = acc[i][2] + bb0.z; o0.w = acc[i][3] + bb0.w;
        o1.x = acc[i][4] + bb1.x; o1.y = acc[i][5] + bb1.y;
        o1.z = acc[i][6] + bb1.z; o1.w = acc[i][7] + bb1.w;
        *(float4*)(C + (size_t)m * N + nBase + tx * 4)      = o0;
        *(float4*)(C + (size_t)m * N + nBase + tx * 4 + 64) = o1;
    }
}

// ---------------------------------------------------------------------------
// LIF scan: one thread per neuron (b,h); U=32 prefetch double-buffer (R3's
// measured-best config: 4MB in flight > 2.4MB BW-latency product).
// In-place safe when cur aliases spk (read t precedes write t per thread).
// ---------------------------------------------------------------------------
__global__ __launch_bounds__(64) void snn_scan(
    const float* cur, float* spk, float* vf, float* iff,
    int T, int H)
{
    const int idx = blockIdx.x * blockDim.x + threadIdx.x; // 0..B*H-1
    const int h = idx & (H - 1);
    const int b = idx >> 10; // H = 1024
    const size_t base = ((size_t)b * T) * H + h;

    constexpr int U = 32;
    float ca[U];
#pragma unroll
    for (int j = 0; j < U; ++j) ca[j] = cur[base + (size_t)j * H];

    float v = 0.f, ii = 0.f;
    for (int t0 = 0; t0 < T; t0 += U) {
        float cb[U];
        const bool pref = (t0 + U) < T;
#pragma unroll
        for (int j = 0; j < U; ++j)
            cb[j] = pref ? cur[base + (size_t)(t0 + U + j) * H] : 0.f;
#pragma unroll
        for (int j = 0; j < U; ++j) {
            const float v_dec = v + 0.1f * ((0.0f - v) + ii);
            const float i_dec = ii - 0.2f * ii;
            const float z = (v_dec > 1.0f) ? 1.0f : 0.0f;
            v  = (v_dec > 1.0f) ? 0.0f : v_dec;
            ii = i_dec + ca[j];
            spk[base + (size_t)(t0 + j) * H] = z;
        }
#pragma unroll
        for (int j = 0; j < U; ++j) ca[j] = cb[j];
    }
    vf[idx]  = v;
    iff[idx] = ii;
}

// ---------------------------------------------------------------------------
extern "C" void kernel_launch(void* const* d_in, const int* in_sizes, int n_in,
                              void* d_out, int out_size, void* d_ws, size_t ws_size,
                              hipStream_t stream) {
    const int B = 32, T = 2048, I = 512, H = 1024;
    const int M = B * T, N = H, K = I;

    const float* x    = (const float*)d_in[0];
    const float* W    = (const float*)d_in[1];
    const float* bias = (const float*)d_in[2];

    float* out    = (float*)d_out;
    float* spikes = out;                        // [B,T,H]
    float* vf     = out + (size_t)B * T * H;    // [B,H]
    float* iff    = vf + (size_t)B * H;         // [B,H]

    const size_t curBytes = (size_t)B * T * H * sizeof(float);
    float* curbuf = (ws_size >= curBytes) ? (float*)d_ws : spikes;

    dim3 grid(N / BN, M / BM); // (8, 512)
    snn_gemm_f32<<<grid, 256, 0, stream>>>(x, W, bias, curbuf, M, N, K);

    const int nNeuron = B * H; // 32768
    snn_scan<<<nNeuron / 64, 64, 0, stream>>>(curbuf, spikes, vf, iff, T, H);
}

// Round 9
// 2501.173 us; speedup vs baseline: 3.4074x; 3.4074x over previous
//
#include <hip/hip_runtime.h>

// Problem dims: x[B,T,I], W[H,I], b[H];  B=32, T=2048, I=512, H=1024.
// out = spikes[B,T,H] fp32, then v_f[B,H], then i_f[B,H].
//
// NUMERICS CONTRACT: current[m,n] accumulated as an fp32 fmaf chain over k
// ascending -> bit-identical to reference (absmax 0.0 across R3/R4/R6/R8).
// Spikes are a hard threshold; do NOT reassociate (no split-K, no MFMA).
//
// R9 = R7 + __launch_bounds__(256). REGISTER RULES (hard-won):
//   - plain __launch_bounds__(256): VGPR budget 256 -> R3/R6 got 172-184, OK.
//   - __launch_bounds__(256,2): budget 128 -> R4 spilled (44GB scratch).
//   - no launch_bounds: default 1024-thread cap -> 64 VGPRs -> R8 spilled.
// Design: A (X) in LDS [k][m] (conflict-free); B (W) fragments from global
// (L2-resident) with manual one-group-ahead register double-buffer (bqX/bqY)
// so every load has ~512cy of independent FMA cover (R6 showed immediate
// consumption = latency-exposed, VALUBusy 25%).

static constexpr int BM = 128, BN = 128, BK = 16;

__device__ __forceinline__ void load_b(
    float4 (&dst)[8], const float* wp0, const float* wp1, int K, int koff)
{
#pragma unroll
    for (int r = 0; r < 4; ++r) {
        dst[r]     = *(const float4*)(wp0 + (size_t)r * K + koff);
        dst[r + 4] = *(const float4*)(wp1 + (size_t)r * K + koff);
    }
}

__device__ __forceinline__ void fma_group(
    const float4 (&src)[8],
    const float (*as)[BM + 4],   // pre-offset to this group's first k-row
    int ty,
    float (&acc)[8][8])
{
#pragma unroll
    for (int kk = 0; kk < 4; ++kk) {
        float a[8];
        *(float4*)&a[0] = *(const float4*)&as[kk][ty * 4];
        *(float4*)&a[4] = *(const float4*)&as[kk][ty * 4 + 64];
        float bv[8];
#pragma unroll
        for (int j = 0; j < 8; ++j)
            bv[j] = (kk == 0) ? src[j].x : (kk == 1) ? src[j].y
                  : (kk == 2) ? src[j].z : src[j].w;
#pragma unroll
        for (int i = 0; i < 8; ++i)
#pragma unroll
            for (int j = 0; j < 8; ++j)
                acc[i][j] = fmaf(a[i], bv[j], acc[i][j]);
    }
}

__global__ __launch_bounds__(256) void snn_gemm_f32(
    const float* __restrict__ X,    // [M,K]
    const float* __restrict__ Wt,   // [N,K]
    const float* __restrict__ bias, // [N]
    float* __restrict__ C,          // [M,N]
    int M, int N, int K)
{
    __shared__ float As[2][BK][BM + 4]; // [k][m], stride 132 floats

    const int tid   = threadIdx.x;
    const int mBase = blockIdx.y * BM;
    const int nBase = blockIdx.x * BN;

    // A loader: each thread brings 2 float4 (rows lrow, lrow+64; k-quad lkq)
    const int lrow = tid >> 2;        // 0..63
    const int lkq  = (tid & 3) << 2;  // 0,4,8,12

    // compute mapping: 16x16 threads, 8x8 micro-tile (split 4+4 at +64)
    const int tx = tid & 15;
    const int ty = tid >> 4;

    const float* Xp = X + (size_t)(mBase + lrow) * K + lkq;
    const size_t Xrow64 = (size_t)64 * K;

    // B row pointers: rows nBase+tx*4+{0..3} and +64 (k-contiguous in W)
    const float* wp0 = Wt + (size_t)(nBase + tx * 4) * K;
    const float* wp1 = wp0 + (size_t)64 * K;

    float acc[8][8];
#pragma unroll
    for (int i = 0; i < 8; ++i)
#pragma unroll
        for (int j = 0; j < 8; ++j) acc[i][j] = 0.f;

    float4 ra0, ra1;
    float4 bqX[8], bqY[8];

    // prologue: stage A k-tile 0 into buffer 0; load B group 0 into bqX
    ra0 = *(const float4*)(Xp);
    ra1 = *(const float4*)(Xp + Xrow64);
    As[0][lkq + 0][lrow] = ra0.x; As[0][lkq + 1][lrow] = ra0.y;
    As[0][lkq + 2][lrow] = ra0.z; As[0][lkq + 3][lrow] = ra0.w;
    As[0][lkq + 0][lrow + 64] = ra1.x; As[0][lkq + 1][lrow + 64] = ra1.y;
    As[0][lkq + 2][lrow + 64] = ra1.z; As[0][lkq + 3][lrow + 64] = ra1.w;
    load_b(bqX, wp0, wp1, K, 0);
    __syncthreads();

    const int nk = K / BK; // 32
#pragma unroll 1
    for (int kt = 0; kt < nk; ++kt) {
        const int cur  = kt & 1;
        const bool more = (kt + 1) < nk;
        const int kb   = kt * BK;
        const int kbn  = more ? (kt + 1) * BK : 0;

        // prefetch next A k-tile into registers (covered by 4 FMA groups)
        if (more) {
            ra0 = *(const float4*)(Xp + kbn);
            ra1 = *(const float4*)(Xp + kbn + Xrow64);
        }

        const float (*as)[BM + 4] = As[cur];

        // phase g0: issue loads for g1 into bqY, compute g0 from bqX
        load_b(bqY, wp0, wp1, K, kb + 4);
        fma_group(bqX, as + 0, ty, acc);
        // phase g1: issue loads for g2 into bqX, compute g1 from bqY
        load_b(bqX, wp0, wp1, K, kb + 8);
        fma_group(bqY, as + 4, ty, acc);
        // phase g2
        load_b(bqY, wp0, wp1, K, kb + 12);
        fma_group(bqX, as + 8, ty, acc);
        // phase g3: issue loads for NEXT kt's g0 into bqX
        load_b(bqX, wp0, wp1, K, kbn);
        fma_group(bqY, as + 12, ty, acc);

        if (more) {
            const int nxt = cur ^ 1;
            As[nxt][lkq + 0][lrow] = ra0.x; As[nxt][lkq + 1][lrow] = ra0.y;
            As[nxt][lkq + 2][lrow] = ra0.z; As[nxt][lkq + 3][lrow] = ra0.w;
            As[nxt][lkq + 0][lrow + 64] = ra1.x; As[nxt][lkq + 1][lrow + 64] = ra1.y;
            As[nxt][lkq + 2][lrow + 64] = ra1.z; As[nxt][lkq + 3][lrow + 64] = ra1.w;
        }
        __syncthreads();
    }

    // epilogue: bias + coalesced float4 stores
    const float4 bb0 = *(const float4*)(bias + nBase + tx * 4);
    const float4 bb1 = *(const float4*)(bias + nBase + tx * 4 + 64);
#pragma unroll
    for (int i = 0; i < 8; ++i) {
        const int m = mBase + ty * 4 + (i & 3) + ((i >> 2) << 6);
        float4 o0, o1;
        o0.x = acc[i][0] + bb0.x; o0.y = acc[i][1] + bb0.y;
        o0.z = acc[i][2] + bb0.z; o0.w = acc[i][3] + bb0.w;
        o1.x = acc[i][4] + bb1.x; o1.y = acc[i][5] + bb1.y;
        o1.z = acc[i][6] + bb1.z; o1.w = acc[i][7] + bb1.w;
        *(float4*)(C + (size_t)m * N + nBase + tx * 4)      = o0;
        *(float4*)(C + (size_t)m * N + nBase + tx * 4 + 64) = o1;
    }
}

// ---------------------------------------------------------------------------
// LIF scan: one thread per neuron (b,h); U=32 prefetch double-buffer.
// In-place safe when cur aliases spk (read t precedes write t per thread).
// ---------------------------------------------------------------------------
__global__ __launch_bounds__(64) void snn_scan(
    const float* cur, float* spk, float* vf, float* iff,
    int T, int H)
{
    const int idx = blockIdx.x * blockDim.x + threadIdx.x; // 0..B*H-1
    const int h = idx & (H - 1);
    const int b = idx >> 10; // H = 1024
    const size_t base = ((size_t)b * T) * H + h;

    constexpr int U = 32;
    float ca[U];
#pragma unroll
    for (int j = 0; j < U; ++j) ca[j] = cur[base + (size_t)j * H];

    float v = 0.f, ii = 0.f;
    for (int t0 = 0; t0 < T; t0 += U) {
        float cb[U];
        const bool pref = (t0 + U) < T;
#pragma unroll
        for (int j = 0; j < U; ++j)
            cb[j] = pref ? cur[base + (size_t)(t0 + U + j) * H] : 0.f;
#pragma unroll
        for (int j = 0; j < U; ++j) {
            const float v_dec = v + 0.1f * ((0.0f - v) + ii);
            const float i_dec = ii - 0.2f * ii;
            const float z = (v_dec > 1.0f) ? 1.0f : 0.0f;
            v  = (v_dec > 1.0f) ? 0.0f : v_dec;
            ii = i_dec + ca[j];
            spk[base + (size_t)(t0 + j) * H] = z;
        }
#pragma unroll
        for (int j = 0; j < U; ++j) ca[j] = cb[j];
    }
    vf[idx]  = v;
    iff[idx] = ii;
}

// ---------------------------------------------------------------------------
extern "C" void kernel_launch(void* const* d_in, const int* in_sizes, int n_in,
                              void* d_out, int out_size, void* d_ws, size_t ws_size,
                              hipStream_t stream) {
    const int B = 32, T = 2048, I = 512, H = 1024;
    const int M = B * T, N = H, K = I;

    const float* x    = (const float*)d_in[0];
    const float* W    = (const float*)d_in[1];
    const float* bias = (const float*)d_in[2];

    float* out    = (float*)d_out;
    float* spikes = out;                        // [B,T,H]
    float* vf     = out + (size_t)B * T * H;    // [B,H]
    float* iff    = vf + (size_t)B * H;         // [B,H]

    const size_t curBytes = (size_t)B * T * H * sizeof(float);
    float* curbuf = (ws_size >= curBytes) ? (float*)d_ws : spikes;

    dim3 grid(N / BN, M / BM); // (8, 512)
    snn_gemm_f32<<<grid, 256, 0, stream>>>(x, W, bias, curbuf, M, N, K);

    const int nNeuron = B * H; // 32768
    snn_scan<<<nNeuron / 64, 64, 0, stream>>>(curbuf, spikes, vf, iff, T, H);
}